// Round 1
// baseline (1385.158 us; speedup 1.0000x reference)
//
#include <hip/hip_runtime.h>
#include <math.h>

#define NEG_SLOPE 0.2f

// ---- monotonic float<->uint encoding for atomicMax on floats ----
__device__ __forceinline__ unsigned enc_f(float f) {
    unsigned u = __float_as_uint(f);
    return (u & 0x80000000u) ? ~u : (u | 0x80000000u);
}
__device__ __forceinline__ float dec_f(unsigned u) {
    u = (u & 0x80000000u) ? (u & 0x7FFFFFFFu) : ~u;
    return __uint_as_float(u);
}

// K0: weights = softmax(alpha), 4 elements, single thread
__global__ void softmax4_kernel(const float* __restrict__ alpha, float* __restrict__ w) {
    float m = alpha[0];
    for (int i = 1; i < 4; i++) m = fmaxf(m, alpha[i]);
    float e[4], s = 0.f;
    for (int i = 0; i < 4; i++) { e[i] = expf(alpha[i] - m); s += e[i]; }
    for (int i = 0; i < 4; i++) w[i] = e[i] / s;
}

// K1: h = x @ W_gat  (N x 11 @ 11 x 64), plus a_src = h.att_src, a_dst = h.att_dst
__global__ __launch_bounds__(256) void gat_input_kernel(
    const float* __restrict__ x, const float* __restrict__ Wg,
    const float* __restrict__ att_src, const float* __restrict__ att_dst,
    float* __restrict__ h, float* __restrict__ a_src, float* __restrict__ a_dst, int N)
{
    __shared__ float Wl[11 * 64];
    int tid = threadIdx.x;
    for (int i = tid; i < 11 * 64; i += 256) Wl[i] = Wg[i];
    __syncthreads();
    int lane = tid & 63;
    int n = blockIdx.x * 4 + (tid >> 6);
    if (n >= N) return;
    float acc = 0.f;
    #pragma unroll
    for (int k = 0; k < 11; k++) acc += x[n * 11 + k] * Wl[k * 64 + lane];
    h[(size_t)n * 64 + lane] = acc;
    float ps = acc * att_src[lane];
    float pd = acc * att_dst[lane];
    for (int off = 32; off; off >>= 1) {
        ps += __shfl_down(ps, off, 64);
        pd += __shfl_down(pd, off, 64);
    }
    if (lane == 0) { a_src[n] = ps; a_dst[n] = pd; }
}

// K2: per (edge + self-loop): logit max into maxlog[dst]; deg[dst] += 1 for real edges
__global__ __launch_bounds__(256) void edge_max_deg_kernel(
    const int* __restrict__ src, const int* __restrict__ dst,
    const float* __restrict__ a_src, const float* __restrict__ a_dst,
    unsigned* __restrict__ maxlog, float* __restrict__ deg, int E, int N)
{
    int i = blockIdx.x * 256 + threadIdx.x;
    if (i >= E + N) return;
    int s, d;
    if (i < E) { s = src[i]; d = dst[i]; atomicAdd(&deg[d], 1.0f); }
    else       { s = i - E; d = s; }
    float a = a_src[s] + a_dst[d];
    float logit = a > 0.f ? a : NEG_SLOPE * a;
    atomicMax(&maxlog[d], enc_f(logit));
}

// K3: wave per (edge + self-loop): num[dst][c] += w*h[src][c]; ssum[dst] += w
__global__ __launch_bounds__(256) void edge_accum_kernel(
    const int* __restrict__ src, const int* __restrict__ dst,
    const float* __restrict__ a_src, const float* __restrict__ a_dst,
    const unsigned* __restrict__ maxlog, const float* __restrict__ h,
    float* __restrict__ num, float* __restrict__ ssum, int E, int N)
{
    int item = blockIdx.x * 4 + (threadIdx.x >> 6);
    int lane = threadIdx.x & 63;
    if (item >= E + N) return;
    int s, d;
    if (item < E) { s = src[item]; d = dst[item]; }
    else          { s = item - E; d = s; }
    float a = a_src[s] + a_dst[d];
    float logit = a > 0.f ? a : NEG_SLOPE * a;
    float w = expf(logit - dec_f(maxlog[d]));
    atomicAdd(&num[(size_t)d * 64 + lane], w * h[(size_t)s * 64 + lane]);
    if (lane == 0) atomicAdd(&ssum[d], w);
}

// K4: h_gat = num/(ssum+eps) + b ; outf = w0*h_gat ; num reset to 0 (reused as agg)
__global__ __launch_bounds__(256) void gat_finalize_kernel(
    float* __restrict__ num, const float* __restrict__ ssum,
    const float* __restrict__ b, const float* __restrict__ wsm,
    float* __restrict__ h_gat, float* __restrict__ outf, int N)
{
    int n = blockIdx.x * 4 + (threadIdx.x >> 6);
    int lane = threadIdx.x & 63;
    if (n >= N) return;
    size_t idx = (size_t)n * 64 + lane;
    float v = num[idx] / (ssum[n] + 1e-16f) + b[lane];
    h_gat[idx] = v;
    outf[idx] = wsm[0] * v;
    num[idx] = 0.f;
}

// K5: wave per edge: agg[dst][c] += hin[src][c]
__global__ __launch_bounds__(256) void sage_agg_kernel(
    const int* __restrict__ src, const int* __restrict__ dst,
    const float* __restrict__ hin, float* __restrict__ agg, int E)
{
    int e = blockIdx.x * 4 + (threadIdx.x >> 6);
    int lane = threadIdx.x & 63;
    if (e >= E) return;
    int s = src[e], d = dst[e];
    atomicAdd(&agg[(size_t)d * 64 + lane], hin[(size_t)s * 64 + lane]);
}

// K6: hout = (agg/max(deg,1)) @ Wl + hin @ Wr + b ; outf += w*hout ; optional agg reset
__global__ __launch_bounds__(256) void sage_finalize_kernel(
    const float* __restrict__ hin, float* __restrict__ agg, const float* __restrict__ deg,
    const float* __restrict__ Wlp, const float* __restrict__ Wrp, const float* __restrict__ b,
    const float* __restrict__ wsm, int widx,
    float* __restrict__ hout, float* __restrict__ outf, int N, int reset)
{
    __shared__ float Wl[64 * 64];
    __shared__ float Wr[64 * 64];
    int tid = threadIdx.x;
    for (int i = tid; i < 4096; i += 256) { Wl[i] = Wlp[i]; Wr[i] = Wrp[i]; }
    __syncthreads();
    int n = blockIdx.x * 4 + (tid >> 6);
    int lane = tid & 63;
    if (n >= N) return;
    size_t idx = (size_t)n * 64 + lane;
    float hd = hin[idx];
    float md = agg[idx] / fmaxf(deg[n], 1.0f);
    float acc = b[lane];
    #pragma unroll 16
    for (int k = 0; k < 64; k++) {
        float mk = __shfl(md, k, 64);
        float hk = __shfl(hd, k, 64);
        acc += mk * Wl[k * 64 + lane] + hk * Wr[k * 64 + lane];
    }
    if (hout) hout[idx] = acc;
    outf[idx] += wsm[widx] * acc;
    if (reset) agg[idx] = 0.f;
}

// K7: wave per label-edge: out[e] = dot(outf[a], outf[b]) over 64 dims
__global__ __launch_bounds__(256) void link_pred_kernel(
    const int* __restrict__ eli, const float* __restrict__ outf,
    float* __restrict__ out, int EL)
{
    int e = blockIdx.x * 4 + (threadIdx.x >> 6);
    int lane = threadIdx.x & 63;
    if (e >= EL) return;
    int a = eli[e], b = eli[EL + e];
    float p = outf[(size_t)a * 64 + lane] * outf[(size_t)b * 64 + lane];
    for (int off = 32; off; off >>= 1) p += __shfl_down(p, off, 64);
    if (lane == 0) out[e] = p;
}

extern "C" void kernel_launch(void* const* d_in, const int* in_sizes, int n_in,
                              void* d_out, int out_size, void* d_ws, size_t ws_size,
                              hipStream_t stream)
{
    const float* x      = (const float*)d_in[0];
    const int*   ei     = (const int*)d_in[1];
    const int*   eli    = (const int*)d_in[2];
    const float* Wg     = (const float*)d_in[3];
    const float* att_s  = (const float*)d_in[4];
    const float* att_d  = (const float*)d_in[5];
    const float* bg     = (const float*)d_in[6];
    const float* W1l    = (const float*)d_in[7];
    const float* W1r    = (const float*)d_in[8];
    const float* b1     = (const float*)d_in[9];
    const float* W2l    = (const float*)d_in[10];
    const float* W2r    = (const float*)d_in[11];
    const float* b2     = (const float*)d_in[12];
    const float* alpha  = (const float*)d_in[13];

    const int N  = in_sizes[0] / 11;
    const int E  = in_sizes[1] / 2;
    const int EL = in_sizes[2] / 2;

    const int* src = ei;
    const int* dst = ei + E;

    // workspace layout (floats)
    float* A = (float*)d_ws;                 // N*64: h_gat, then h1 (in-place)
    float* B = A + (size_t)N * 64;           // N*64: GAT numerator, then SAGE agg (reused)
    float* D = B + (size_t)N * 64;           // N*64: weighted output accumulator
    float* a_src  = D + (size_t)N * 64;      // N
    float* a_dst  = a_src + N;               // N
    unsigned* maxlog = (unsigned*)(a_dst + N); // N
    float* ssum = (float*)(maxlog + N);      // N
    float* deg  = ssum + N;                  // N
    float* wsm  = deg + N;                   // 4

    // zero-init accumulators (re-poisoned to 0xAA before every launch)
    hipMemsetAsync(B, 0, (size_t)N * 64 * sizeof(float), stream);
    hipMemsetAsync(maxlog, 0, (size_t)N * sizeof(unsigned), stream); // decodes to -NaN (below all)
    hipMemsetAsync(ssum, 0, (size_t)N * sizeof(float), stream);
    hipMemsetAsync(deg, 0, (size_t)N * sizeof(float), stream);

    softmax4_kernel<<<1, 1, 0, stream>>>(alpha, wsm);

    gat_input_kernel<<<(N + 3) / 4, 256, 0, stream>>>(x, Wg, att_s, att_d, A, a_src, a_dst, N);

    int items = E + N;
    edge_max_deg_kernel<<<(items + 255) / 256, 256, 0, stream>>>(src, dst, a_src, a_dst, maxlog, deg, E, N);

    edge_accum_kernel<<<(items + 3) / 4, 256, 0, stream>>>(src, dst, a_src, a_dst, maxlog, A, B, ssum, E, N);

    gat_finalize_kernel<<<(N + 3) / 4, 256, 0, stream>>>(B, ssum, bg, wsm, A, D, N);

    // SAGE layer 1: input A (h_gat), agg into B, h1 written back into A
    sage_agg_kernel<<<(E + 3) / 4, 256, 0, stream>>>(src, dst, A, B, E);
    sage_finalize_kernel<<<(N + 3) / 4, 256, 0, stream>>>(A, B, deg, W1l, W1r, b1, wsm, 2, A, D, N, 1);

    // SAGE layer 2: input A (h1), agg into B, h2 only folded into D
    sage_agg_kernel<<<(E + 3) / 4, 256, 0, stream>>>(src, dst, A, B, E);
    sage_finalize_kernel<<<(N + 3) / 4, 256, 0, stream>>>(A, B, deg, W2l, W2r, b2, wsm, 3, nullptr, D, N, 0);

    link_pred_kernel<<<(EL + 3) / 4, 256, 0, stream>>>(eli, D, (float*)d_out, EL);
}

// Round 2
// 812.832 us; speedup vs baseline: 1.7041x; 1.7041x over previous
//
#include <hip/hip_runtime.h>
#include <math.h>
#include <float.h>

#define NEG_SLOPE 0.2f

// K0: weights = softmax(alpha), 4 elements, single thread
__global__ void softmax4_kernel(const float* __restrict__ alpha, float* __restrict__ w) {
    float m = alpha[0];
    for (int i = 1; i < 4; i++) m = fmaxf(m, alpha[i]);
    float e[4], s = 0.f;
    for (int i = 0; i < 4; i++) { e[i] = expf(alpha[i] - m); s += e[i]; }
    for (int i = 0; i < 4; i++) w[i] = e[i] / s;
}

// K1: h = x @ W_gat  (N x 11 @ 11 x 64), plus a_src = h.att_src, a_dst = h.att_dst
__global__ __launch_bounds__(256) void gat_input_kernel(
    const float* __restrict__ x, const float* __restrict__ Wg,
    const float* __restrict__ att_src, const float* __restrict__ att_dst,
    float* __restrict__ h, float* __restrict__ a_src, float* __restrict__ a_dst, int N)
{
    __shared__ float Wl[11 * 64];
    int tid = threadIdx.x;
    for (int i = tid; i < 11 * 64; i += 256) Wl[i] = Wg[i];
    __syncthreads();
    int lane = tid & 63;
    int n = blockIdx.x * 4 + (tid >> 6);
    if (n >= N) return;
    float acc = 0.f;
    #pragma unroll
    for (int k = 0; k < 11; k++) acc += x[n * 11 + k] * Wl[k * 64 + lane];
    h[(size_t)n * 64 + lane] = acc;
    float ps = acc * att_src[lane];
    float pd = acc * att_dst[lane];
    for (int off = 32; off; off >>= 1) {
        ps += __shfl_down(ps, off, 64);
        pd += __shfl_down(pd, off, 64);
    }
    if (lane == 0) { a_src[n] = ps; a_dst[n] = pd; }
}

// ---- CSR construction ----
__global__ __launch_bounds__(256) void csr_count_kernel(
    const int* __restrict__ dst, int* __restrict__ cnt, int E)
{
    int i = blockIdx.x * 256 + threadIdx.x;
    if (i < E) atomicAdd(&cnt[dst[i]], 1);
}

// scan pass A: per-block (1024-chunk) sums
__global__ __launch_bounds__(256) void scan_reduce_kernel(
    const int* __restrict__ cnt, int* __restrict__ bsum, int N)
{
    __shared__ int s[256];
    int t = threadIdx.x;
    int base = blockIdx.x * 1024 + t * 4;
    int sum = 0;
    #pragma unroll
    for (int j = 0; j < 4; j++) { int idx = base + j; if (idx < N) sum += cnt[idx]; }
    s[t] = sum; __syncthreads();
    for (int off = 128; off; off >>= 1) {
        if (t < off) s[t] += s[t + off];
        __syncthreads();
    }
    if (t == 0) bsum[blockIdx.x] = s[0];
}

// scan pass B: single-block exclusive scan of block sums (NB <= 256)
__global__ __launch_bounds__(256) void scan_spine_kernel(
    const int* __restrict__ bsum, int* __restrict__ boff, int NB)
{
    __shared__ int s[256];
    int t = threadIdx.x;
    int v = (t < NB) ? bsum[t] : 0;
    s[t] = v; __syncthreads();
    for (int off = 1; off < 256; off <<= 1) {
        int x = (t >= off) ? s[t - off] : 0;
        __syncthreads();
        s[t] += x;
        __syncthreads();
    }
    if (t < NB) boff[t] = s[t] - v;
}

// scan pass C: per-block exclusive scan + spine offset -> rowstart
__global__ __launch_bounds__(256) void scan_apply_kernel(
    const int* __restrict__ cnt, const int* __restrict__ boff,
    int* __restrict__ rowstart, int N)
{
    __shared__ int s[256];
    int t = threadIdx.x;
    int base = blockIdx.x * 1024;
    int v[4]; int sum = 0;
    #pragma unroll
    for (int j = 0; j < 4; j++) {
        int idx = base + t * 4 + j;
        v[j] = (idx < N) ? cnt[idx] : 0;
        sum += v[j];
    }
    s[t] = sum; __syncthreads();
    for (int off = 1; off < 256; off <<= 1) {
        int x = (t >= off) ? s[t - off] : 0;
        __syncthreads();
        s[t] += x;
        __syncthreads();
    }
    int ex = s[t] - sum + boff[blockIdx.x];
    #pragma unroll
    for (int j = 0; j < 4; j++) {
        int idx = base + t * 4 + j;
        if (idx < N) rowstart[idx] = ex;
        ex += v[j];
    }
}

__global__ __launch_bounds__(256) void csr_scatter_kernel(
    const int* __restrict__ src, const int* __restrict__ dst,
    const int* __restrict__ rowstart, int* __restrict__ cursor,
    int* __restrict__ csr, int E)
{
    int i = blockIdx.x * 256 + threadIdx.x;
    if (i >= E) return;
    int d = dst[i];
    int pos = rowstart[d] + atomicAdd(&cursor[d], 1);
    csr[pos] = src[i];
}

// K2: GAT gather — wave per dst node, online softmax over self-loop + in-edges
__global__ __launch_bounds__(256) void gat_gather_kernel(
    const float* __restrict__ h, const float* __restrict__ a_src,
    const float* __restrict__ a_dst, const float* __restrict__ bg,
    const int* __restrict__ rowstart, const int* __restrict__ cnt,
    const int* __restrict__ csr, const float* __restrict__ wsm,
    float* __restrict__ hgat, float* __restrict__ outD, int N)
{
    int d = blockIdx.x * 4 + (threadIdx.x >> 6);
    int lane = threadIdx.x & 63;
    if (d >= N) return;
    float ad = a_dst[d];
    int beg = rowstart[d], deg = cnt[d];
    // self-loop init
    float a0 = a_src[d] + ad;
    float m = a0 > 0.f ? a0 : NEG_SLOPE * a0;   // running max
    float l = 1.0f;                              // running sum (self-loop w = 1 at scale m)
    float acc = h[(size_t)d * 64 + lane];        // running numerator (channel = lane)
    for (int base = 0; base < deg; base += 64) {
        int eidx = base + lane;
        bool valid = eidx < deg;
        int sid = valid ? csr[beg + eidx] : 0;
        float aa = valid ? (a_src[sid] + ad) : 0.f;
        float lg = aa > 0.f ? aa : NEG_SLOPE * aa;
        if (!valid) lg = -FLT_MAX;
        float cm = lg;
        for (int off = 32; off; off >>= 1) cm = fmaxf(cm, __shfl_xor(cm, off, 64));
        float nm = fmaxf(m, cm);
        float scale = expf(m - nm);
        acc *= scale; l *= scale; m = nm;
        float w = valid ? expf(lg - m) : 0.f;
        float ws = w;
        for (int off = 32; off; off >>= 1) ws += __shfl_xor(ws, off, 64);
        l += ws;
        int nvalid = deg - base; if (nvalid > 64) nvalid = 64;
        #pragma unroll 4
        for (int j = 0; j < nvalid; j++) {
            int   sj = __shfl(sid, j, 64);
            float wj = __shfl(w,   j, 64);
            acc += wj * h[(size_t)sj * 64 + lane];
        }
    }
    float out = acc / (l + 1e-16f) + bg[lane];
    size_t idx = (size_t)d * 64 + lane;
    hgat[idx] = out;
    outD[idx] = wsm[0] * out;
}

// K3: fused SAGE layer — gather-mean + (mean@Wl + hin@Wr + b), wave per node
__global__ __launch_bounds__(256) void sage_fused_kernel(
    const float* __restrict__ hin,
    const int* __restrict__ rowstart, const int* __restrict__ cnt,
    const int* __restrict__ csr,
    const float* __restrict__ Wlp, const float* __restrict__ Wrp,
    const float* __restrict__ b, const float* __restrict__ wsm, int widx,
    float* __restrict__ hout, float* __restrict__ outD, int N)
{
    __shared__ float Wl[4096];
    __shared__ float Wr[4096];
    int tid = threadIdx.x;
    for (int i = tid; i < 4096; i += 256) { Wl[i] = Wlp[i]; Wr[i] = Wrp[i]; }
    __syncthreads();
    int d = blockIdx.x * 4 + (tid >> 6);
    int lane = tid & 63;
    if (d >= N) return;
    int beg = rowstart[d], deg = cnt[d];
    float s = 0.f;
    #pragma unroll 4
    for (int k = 0; k < deg; k++) {
        int sid = csr[beg + k];
        s += hin[(size_t)sid * 64 + lane];
    }
    float mean = s / fmaxf((float)deg, 1.0f);
    float hd = hin[(size_t)d * 64 + lane];
    float acc = b[lane];
    #pragma unroll 16
    for (int k = 0; k < 64; k++) {
        acc += __shfl(mean, k, 64) * Wl[k * 64 + lane]
             + __shfl(hd,   k, 64) * Wr[k * 64 + lane];
    }
    size_t idx = (size_t)d * 64 + lane;
    if (hout) hout[idx] = acc;
    outD[idx] += wsm[widx] * acc;
}

// K4: wave per label-edge: out[e] = dot(outf[a], outf[b]) over 64 dims
__global__ __launch_bounds__(256) void link_pred_kernel(
    const int* __restrict__ eli, const float* __restrict__ outf,
    float* __restrict__ out, int EL)
{
    int e = blockIdx.x * 4 + (threadIdx.x >> 6);
    int lane = threadIdx.x & 63;
    if (e >= EL) return;
    int a = eli[e], b = eli[EL + e];
    float p = outf[(size_t)a * 64 + lane] * outf[(size_t)b * 64 + lane];
    for (int off = 32; off; off >>= 1) p += __shfl_down(p, off, 64);
    if (lane == 0) out[e] = p;
}

extern "C" void kernel_launch(void* const* d_in, const int* in_sizes, int n_in,
                              void* d_out, int out_size, void* d_ws, size_t ws_size,
                              hipStream_t stream)
{
    const float* x      = (const float*)d_in[0];
    const int*   ei     = (const int*)d_in[1];
    const int*   eli    = (const int*)d_in[2];
    const float* Wg     = (const float*)d_in[3];
    const float* att_s  = (const float*)d_in[4];
    const float* att_d  = (const float*)d_in[5];
    const float* bg     = (const float*)d_in[6];
    const float* W1l    = (const float*)d_in[7];
    const float* W1r    = (const float*)d_in[8];
    const float* b1     = (const float*)d_in[9];
    const float* W2l    = (const float*)d_in[10];
    const float* W2r    = (const float*)d_in[11];
    const float* b2     = (const float*)d_in[12];
    const float* alpha  = (const float*)d_in[13];

    const int N  = in_sizes[0] / 11;
    const int E  = in_sizes[1] / 2;
    const int EL = in_sizes[2] / 2;

    const int* src = ei;
    const int* dst = ei + E;

    // workspace layout
    float* A        = (float*)d_ws;              // N*64: h, then h1
    float* B        = A + (size_t)N * 64;        // N*64: h_gat
    float* D        = B + (size_t)N * 64;        // N*64: weighted output accumulator
    float* a_src    = D + (size_t)N * 64;        // N
    float* a_dst    = a_src + N;                 // N
    int*   cnt      = (int*)(a_dst + N);         // N (in-degree, real edges)
    int*   rowstart = cnt + N;                   // N
    int*   cursor   = rowstart + N;              // N
    int*   bsum     = cursor + N;                // 256
    int*   boff     = bsum + 256;                // 256
    int*   csr      = boff + 256;                // E (src ids grouped by dst)
    float* wsm      = (float*)(csr + E);         // 4

    hipMemsetAsync(cnt, 0, (size_t)N * sizeof(int), stream);
    hipMemsetAsync(cursor, 0, (size_t)N * sizeof(int), stream);

    softmax4_kernel<<<1, 1, 0, stream>>>(alpha, wsm);

    gat_input_kernel<<<(N + 3) / 4, 256, 0, stream>>>(x, Wg, att_s, att_d, A, a_src, a_dst, N);

    // CSR build
    csr_count_kernel<<<(E + 255) / 256, 256, 0, stream>>>(dst, cnt, E);
    int NB = (N + 1023) / 1024;  // 98 for N=100k (<=256 supported)
    scan_reduce_kernel<<<NB, 256, 0, stream>>>(cnt, bsum, N);
    scan_spine_kernel<<<1, 256, 0, stream>>>(bsum, boff, NB);
    scan_apply_kernel<<<NB, 256, 0, stream>>>(cnt, boff, rowstart, N);
    csr_scatter_kernel<<<(E + 255) / 256, 256, 0, stream>>>(src, dst, rowstart, cursor, csr, E);

    // GAT: read h (A) -> h_gat (B), D = w0*h_gat
    gat_gather_kernel<<<(N + 3) / 4, 256, 0, stream>>>(A, a_src, a_dst, bg,
                                                       rowstart, cnt, csr, wsm, B, D, N);

    // SAGE1: read B -> h1 (A), D += w2*h1
    sage_fused_kernel<<<(N + 3) / 4, 256, 0, stream>>>(B, rowstart, cnt, csr,
                                                       W1l, W1r, b1, wsm, 2, A, D, N);

    // SAGE2: read A, D += w3*h2
    sage_fused_kernel<<<(N + 3) / 4, 256, 0, stream>>>(A, rowstart, cnt, csr,
                                                       W2l, W2r, b2, wsm, 3, nullptr, D, N);

    link_pred_kernel<<<(EL + 3) / 4, 256, 0, stream>>>(eli, D, (float*)d_out, EL);
}

// Round 3
// 744.681 us; speedup vs baseline: 1.8601x; 1.0915x over previous
//
#include <hip/hip_runtime.h>
#include <math.h>
#include <float.h>

#define NEG_SLOPE 0.2f

// K0: weights = softmax(alpha), 4 elements, single thread
__global__ void softmax4_kernel(const float* __restrict__ alpha, float* __restrict__ w) {
    float m = alpha[0];
    for (int i = 1; i < 4; i++) m = fmaxf(m, alpha[i]);
    float e[4], s = 0.f;
    for (int i = 0; i < 4; i++) { e[i] = expf(alpha[i] - m); s += e[i]; }
    for (int i = 0; i < 4; i++) w[i] = e[i] / s;
}

// K1: h = x @ W_gat  (N x 11 @ 11 x 64), plus a_src = h.att_src, a_dst = h.att_dst
__global__ __launch_bounds__(256) void gat_input_kernel(
    const float* __restrict__ x, const float* __restrict__ Wg,
    const float* __restrict__ att_src, const float* __restrict__ att_dst,
    float* __restrict__ h, float* __restrict__ a_src, float* __restrict__ a_dst, int N)
{
    __shared__ float Wl[11 * 64];
    int tid = threadIdx.x;
    for (int i = tid; i < 11 * 64; i += 256) Wl[i] = Wg[i];
    __syncthreads();
    int lane = tid & 63;
    int n = blockIdx.x * 4 + (tid >> 6);
    if (n >= N) return;
    float acc = 0.f;
    #pragma unroll
    for (int k = 0; k < 11; k++) acc += x[n * 11 + k] * Wl[k * 64 + lane];
    h[(size_t)n * 64 + lane] = acc;
    float ps = acc * att_src[lane];
    float pd = acc * att_dst[lane];
    for (int off = 32; off; off >>= 1) {
        ps += __shfl_down(ps, off, 64);
        pd += __shfl_down(pd, off, 64);
    }
    if (lane == 0) { a_src[n] = ps; a_dst[n] = pd; }
}

// ---- CSR construction ----
__global__ __launch_bounds__(256) void csr_count_kernel(
    const int* __restrict__ dst, int* __restrict__ cnt, int E)
{
    int i = blockIdx.x * 256 + threadIdx.x;
    if (i < E) atomicAdd(&cnt[dst[i]], 1);
}

// scan pass A: per-block (1024-chunk) sums
__global__ __launch_bounds__(256) void scan_reduce_kernel(
    const int* __restrict__ cnt, int* __restrict__ bsum, int N)
{
    __shared__ int s[256];
    int t = threadIdx.x;
    int base = blockIdx.x * 1024 + t * 4;
    int sum = 0;
    #pragma unroll
    for (int j = 0; j < 4; j++) { int idx = base + j; if (idx < N) sum += cnt[idx]; }
    s[t] = sum; __syncthreads();
    for (int off = 128; off; off >>= 1) {
        if (t < off) s[t] += s[t + off];
        __syncthreads();
    }
    if (t == 0) bsum[blockIdx.x] = s[0];
}

// scan pass B: single-block exclusive scan of block sums (NB <= 256)
__global__ __launch_bounds__(256) void scan_spine_kernel(
    const int* __restrict__ bsum, int* __restrict__ boff, int NB)
{
    __shared__ int s[256];
    int t = threadIdx.x;
    int v = (t < NB) ? bsum[t] : 0;
    s[t] = v; __syncthreads();
    for (int off = 1; off < 256; off <<= 1) {
        int x = (t >= off) ? s[t - off] : 0;
        __syncthreads();
        s[t] += x;
        __syncthreads();
    }
    if (t < NB) boff[t] = s[t] - v;
}

// scan pass C: per-block exclusive scan + spine offset -> rowstart
__global__ __launch_bounds__(256) void scan_apply_kernel(
    const int* __restrict__ cnt, const int* __restrict__ boff,
    int* __restrict__ rowstart, int N)
{
    __shared__ int s[256];
    int t = threadIdx.x;
    int base = blockIdx.x * 1024;
    int v[4]; int sum = 0;
    #pragma unroll
    for (int j = 0; j < 4; j++) {
        int idx = base + t * 4 + j;
        v[j] = (idx < N) ? cnt[idx] : 0;
        sum += v[j];
    }
    s[t] = sum; __syncthreads();
    for (int off = 1; off < 256; off <<= 1) {
        int x = (t >= off) ? s[t - off] : 0;
        __syncthreads();
        s[t] += x;
        __syncthreads();
    }
    int ex = s[t] - sum + boff[blockIdx.x];
    #pragma unroll
    for (int j = 0; j < 4; j++) {
        int idx = base + t * 4 + j;
        if (idx < N) rowstart[idx] = ex;
        ex += v[j];
    }
}

__global__ __launch_bounds__(256) void csr_scatter_kernel(
    const int* __restrict__ src, const int* __restrict__ dst,
    const int* __restrict__ rowstart, int* __restrict__ cursor,
    int* __restrict__ csr, int E)
{
    int i = blockIdx.x * 256 + threadIdx.x;
    if (i >= E) return;
    int d = dst[i];
    int pos = rowstart[d] + atomicAdd(&cursor[d], 1);
    csr[pos] = src[i];
}

// K2: GAT gather — wave per dst node, online softmax over self-loop + in-edges
__global__ __launch_bounds__(256) void gat_gather_kernel(
    const float* __restrict__ h, const float* __restrict__ a_src,
    const float* __restrict__ a_dst, const float* __restrict__ bg,
    const int* __restrict__ rowstart, const int* __restrict__ cnt,
    const int* __restrict__ csr, const float* __restrict__ wsm,
    float* __restrict__ hgat, float* __restrict__ outD, int N)
{
    int d = blockIdx.x * 4 + (threadIdx.x >> 6);
    int lane = threadIdx.x & 63;
    if (d >= N) return;
    float ad = a_dst[d];
    int beg = rowstart[d], deg = cnt[d];
    // self-loop init
    float a0 = a_src[d] + ad;
    float m = a0 > 0.f ? a0 : NEG_SLOPE * a0;   // running max
    float l = 1.0f;                              // running sum (self-loop w = 1 at scale m)
    float acc = h[(size_t)d * 64 + lane];        // running numerator (channel = lane)
    for (int base = 0; base < deg; base += 64) {
        int eidx = base + lane;
        bool valid = eidx < deg;
        int sid = valid ? csr[beg + eidx] : 0;
        float aa = valid ? (a_src[sid] + ad) : 0.f;
        float lg = aa > 0.f ? aa : NEG_SLOPE * aa;
        if (!valid) lg = -FLT_MAX;
        float cm = lg;
        for (int off = 32; off; off >>= 1) cm = fmaxf(cm, __shfl_xor(cm, off, 64));
        float nm = fmaxf(m, cm);
        float scale = expf(m - nm);
        acc *= scale; l *= scale; m = nm;
        float w = valid ? expf(lg - m) : 0.f;
        float ws = w;
        for (int off = 32; off; off >>= 1) ws += __shfl_xor(ws, off, 64);
        l += ws;
        int nvalid = deg - base; if (nvalid > 64) nvalid = 64;
        int j = 0;
        for (; j + 4 <= nvalid; j += 4) {
            int   s0 = __shfl(sid, j,     64); float w0 = __shfl(w, j,     64);
            int   s1 = __shfl(sid, j + 1, 64); float w1 = __shfl(w, j + 1, 64);
            int   s2 = __shfl(sid, j + 2, 64); float w2 = __shfl(w, j + 2, 64);
            int   s3 = __shfl(sid, j + 3, 64); float w3 = __shfl(w, j + 3, 64);
            float v0 = h[(size_t)s0 * 64 + lane];
            float v1 = h[(size_t)s1 * 64 + lane];
            float v2 = h[(size_t)s2 * 64 + lane];
            float v3 = h[(size_t)s3 * 64 + lane];
            acc += w0 * v0 + w1 * v1 + w2 * v2 + w3 * v3;
        }
        for (; j < nvalid; j++) {
            int   sj = __shfl(sid, j, 64);
            float wj = __shfl(w,   j, 64);
            acc += wj * h[(size_t)sj * 64 + lane];
        }
    }
    float out = acc / (l + 1e-16f) + bg[lane];
    size_t idx = (size_t)d * 64 + lane;
    hgat[idx] = out;
    outD[idx] = wsm[0] * out;
}

// K3: fused SAGE layer — gather-mean + (mean@Wl + hin@Wr + b)
// block = 1024 (16 waves share one LDS weight copy), wave per node
__global__ __launch_bounds__(1024) void sage_fused_kernel(
    const float* __restrict__ hin,
    const int* __restrict__ rowstart, const int* __restrict__ cnt,
    const int* __restrict__ csr,
    const float* __restrict__ Wlp, const float* __restrict__ Wrp,
    const float* __restrict__ b, const float* __restrict__ wsm, int widx,
    float* __restrict__ hout, float* __restrict__ outD, int N)
{
    __shared__ float Wl[4096];
    __shared__ float Wr[4096];
    int tid = threadIdx.x;
    for (int i = tid; i < 4096; i += 1024) { Wl[i] = Wlp[i]; Wr[i] = Wrp[i]; }
    __syncthreads();
    int d = blockIdx.x * 16 + (tid >> 6);
    int lane = tid & 63;
    if (d >= N) return;
    int beg = rowstart[d], deg = cnt[d];
    float s0 = 0.f, s1 = 0.f, s2 = 0.f, s3 = 0.f;
    for (int base = 0; base < deg; base += 64) {
        int nv = deg - base; if (nv > 64) nv = 64;
        int sid = (lane < nv) ? csr[beg + base + lane] : 0;
        int j = 0;
        for (; j + 4 <= nv; j += 4) {
            int i0 = __shfl(sid, j,     64);
            int i1 = __shfl(sid, j + 1, 64);
            int i2 = __shfl(sid, j + 2, 64);
            int i3 = __shfl(sid, j + 3, 64);
            float v0 = hin[(size_t)i0 * 64 + lane];
            float v1 = hin[(size_t)i1 * 64 + lane];
            float v2 = hin[(size_t)i2 * 64 + lane];
            float v3 = hin[(size_t)i3 * 64 + lane];
            s0 += v0; s1 += v1; s2 += v2; s3 += v3;
        }
        for (; j < nv; j++) {
            int i0 = __shfl(sid, j, 64);
            s0 += hin[(size_t)i0 * 64 + lane];
        }
    }
    float s = (s0 + s1) + (s2 + s3);
    float mean = s / fmaxf((float)deg, 1.0f);
    float hd = hin[(size_t)d * 64 + lane];
    float acc = b[lane];
    #pragma unroll 16
    for (int k = 0; k < 64; k++) {
        acc += __shfl(mean, k, 64) * Wl[k * 64 + lane]
             + __shfl(hd,   k, 64) * Wr[k * 64 + lane];
    }
    size_t idx = (size_t)d * 64 + lane;
    if (hout) hout[idx] = acc;
    outD[idx] += wsm[widx] * acc;
}

// K4: wave per label-edge: out[e] = dot(outf[a], outf[b]) over 64 dims
__global__ __launch_bounds__(256) void link_pred_kernel(
    const int* __restrict__ eli, const float* __restrict__ outf,
    float* __restrict__ out, int EL)
{
    int e = blockIdx.x * 4 + (threadIdx.x >> 6);
    int lane = threadIdx.x & 63;
    if (e >= EL) return;
    int a = eli[e], b = eli[EL + e];
    float p = outf[(size_t)a * 64 + lane] * outf[(size_t)b * 64 + lane];
    for (int off = 32; off; off >>= 1) p += __shfl_down(p, off, 64);
    if (lane == 0) out[e] = p;
}

extern "C" void kernel_launch(void* const* d_in, const int* in_sizes, int n_in,
                              void* d_out, int out_size, void* d_ws, size_t ws_size,
                              hipStream_t stream)
{
    const float* x      = (const float*)d_in[0];
    const int*   ei     = (const int*)d_in[1];
    const int*   eli    = (const int*)d_in[2];
    const float* Wg     = (const float*)d_in[3];
    const float* att_s  = (const float*)d_in[4];
    const float* att_d  = (const float*)d_in[5];
    const float* bg     = (const float*)d_in[6];
    const float* W1l    = (const float*)d_in[7];
    const float* W1r    = (const float*)d_in[8];
    const float* b1     = (const float*)d_in[9];
    const float* W2l    = (const float*)d_in[10];
    const float* W2r    = (const float*)d_in[11];
    const float* b2     = (const float*)d_in[12];
    const float* alpha  = (const float*)d_in[13];

    const int N  = in_sizes[0] / 11;
    const int E  = in_sizes[1] / 2;
    const int EL = in_sizes[2] / 2;

    const int* src = ei;
    const int* dst = ei + E;

    // workspace layout
    float* A        = (float*)d_ws;              // N*64: h, then h1
    float* B        = A + (size_t)N * 64;        // N*64: h_gat
    float* D        = B + (size_t)N * 64;        // N*64: weighted output accumulator
    float* a_src    = D + (size_t)N * 64;        // N
    float* a_dst    = a_src + N;                 // N
    int*   cnt      = (int*)(a_dst + N);         // N (in-degree, real edges)
    int*   rowstart = cnt + N;                   // N
    int*   cursor   = rowstart + N;              // N
    int*   bsum     = cursor + N;                // 256
    int*   boff     = bsum + 256;                // 256
    int*   csr      = boff + 256;                // E (src ids grouped by dst)
    float* wsm      = (float*)(csr + E);         // 4

    hipMemsetAsync(cnt, 0, (size_t)N * sizeof(int), stream);
    hipMemsetAsync(cursor, 0, (size_t)N * sizeof(int), stream);

    softmax4_kernel<<<1, 1, 0, stream>>>(alpha, wsm);

    gat_input_kernel<<<(N + 3) / 4, 256, 0, stream>>>(x, Wg, att_s, att_d, A, a_src, a_dst, N);

    // CSR build
    csr_count_kernel<<<(E + 255) / 256, 256, 0, stream>>>(dst, cnt, E);
    int NB = (N + 1023) / 1024;  // 98 for N=100k (<=256 supported)
    scan_reduce_kernel<<<NB, 256, 0, stream>>>(cnt, bsum, N);
    scan_spine_kernel<<<1, 256, 0, stream>>>(bsum, boff, NB);
    scan_apply_kernel<<<NB, 256, 0, stream>>>(cnt, boff, rowstart, N);
    csr_scatter_kernel<<<(E + 255) / 256, 256, 0, stream>>>(src, dst, rowstart, cursor, csr, E);

    // GAT: read h (A) -> h_gat (B), D = w0*h_gat
    gat_gather_kernel<<<(N + 3) / 4, 256, 0, stream>>>(A, a_src, a_dst, bg,
                                                       rowstart, cnt, csr, wsm, B, D, N);

    // SAGE1: read B -> h1 (A), D += w2*h1
    sage_fused_kernel<<<(N + 15) / 16, 1024, 0, stream>>>(B, rowstart, cnt, csr,
                                                          W1l, W1r, b1, wsm, 2, A, D, N);

    // SAGE2: read A, D += w3*h2
    sage_fused_kernel<<<(N + 15) / 16, 1024, 0, stream>>>(A, rowstart, cnt, csr,
                                                          W2l, W2r, b2, wsm, 3, nullptr, D, N);

    link_pred_kernel<<<(EL + 3) / 4, 256, 0, stream>>>(eli, D, (float*)d_out, EL);
}

// Round 4
// 702.365 us; speedup vs baseline: 1.9721x; 1.0602x over previous
//
#include <hip/hip_runtime.h>
#include <math.h>
#include <float.h>

#define NEG_SLOPE 0.2f

// K0: weights = softmax(alpha), 4 elements, single thread
__global__ void softmax4_kernel(const float* __restrict__ alpha, float* __restrict__ w) {
    float m = alpha[0];
    for (int i = 1; i < 4; i++) m = fmaxf(m, alpha[i]);
    float e[4], s = 0.f;
    for (int i = 0; i < 4; i++) { e[i] = expf(alpha[i] - m); s += e[i]; }
    for (int i = 0; i < 4; i++) w[i] = e[i] / s;
}

// K1: h = x @ W_gat  (N x 11 @ 11 x 64), plus a_src = h.att_src, a_dst = h.att_dst
__global__ __launch_bounds__(256) void gat_input_kernel(
    const float* __restrict__ x, const float* __restrict__ Wg,
    const float* __restrict__ att_src, const float* __restrict__ att_dst,
    float* __restrict__ h, float* __restrict__ a_src, float* __restrict__ a_dst, int N)
{
    __shared__ float Wl[11 * 64];
    int tid = threadIdx.x;
    for (int i = tid; i < 11 * 64; i += 256) Wl[i] = Wg[i];
    __syncthreads();
    int lane = tid & 63;
    int n = blockIdx.x * 4 + (tid >> 6);
    if (n >= N) return;
    float acc = 0.f;
    #pragma unroll
    for (int k = 0; k < 11; k++) acc += x[n * 11 + k] * Wl[k * 64 + lane];
    h[(size_t)n * 64 + lane] = acc;
    float ps = acc * att_src[lane];
    float pd = acc * att_dst[lane];
    for (int off = 32; off; off >>= 1) {
        ps += __shfl_down(ps, off, 64);
        pd += __shfl_down(pd, off, 64);
    }
    if (lane == 0) { a_src[n] = ps; a_dst[n] = pd; }
}

// ---- CSR construction ----
__global__ __launch_bounds__(256) void csr_count_kernel(
    const int* __restrict__ dst, int* __restrict__ cnt, int E)
{
    int i = blockIdx.x * 256 + threadIdx.x;
    if (i < E) atomicAdd(&cnt[dst[i]], 1);
}

__global__ __launch_bounds__(256) void scan_reduce_kernel(
    const int* __restrict__ cnt, int* __restrict__ bsum, int N)
{
    __shared__ int s[256];
    int t = threadIdx.x;
    int base = blockIdx.x * 1024 + t * 4;
    int sum = 0;
    #pragma unroll
    for (int j = 0; j < 4; j++) { int idx = base + j; if (idx < N) sum += cnt[idx]; }
    s[t] = sum; __syncthreads();
    for (int off = 128; off; off >>= 1) {
        if (t < off) s[t] += s[t + off];
        __syncthreads();
    }
    if (t == 0) bsum[blockIdx.x] = s[0];
}

__global__ __launch_bounds__(256) void scan_spine_kernel(
    const int* __restrict__ bsum, int* __restrict__ boff, int NB)
{
    __shared__ int s[256];
    int t = threadIdx.x;
    int v = (t < NB) ? bsum[t] : 0;
    s[t] = v; __syncthreads();
    for (int off = 1; off < 256; off <<= 1) {
        int x = (t >= off) ? s[t - off] : 0;
        __syncthreads();
        s[t] += x;
        __syncthreads();
    }
    if (t < NB) boff[t] = s[t] - v;
}

__global__ __launch_bounds__(256) void scan_apply_kernel(
    const int* __restrict__ cnt, const int* __restrict__ boff,
    int* __restrict__ rowstart, int N)
{
    __shared__ int s[256];
    int t = threadIdx.x;
    int base = blockIdx.x * 1024;
    int v[4]; int sum = 0;
    #pragma unroll
    for (int j = 0; j < 4; j++) {
        int idx = base + t * 4 + j;
        v[j] = (idx < N) ? cnt[idx] : 0;
        sum += v[j];
    }
    s[t] = sum; __syncthreads();
    for (int off = 1; off < 256; off <<= 1) {
        int x = (t >= off) ? s[t - off] : 0;
        __syncthreads();
        s[t] += x;
        __syncthreads();
    }
    int ex = s[t] - sum + boff[blockIdx.x];
    #pragma unroll
    for (int j = 0; j < 4; j++) {
        int idx = base + t * 4 + j;
        if (idx < N) rowstart[idx] = ex;
        ex += v[j];
    }
}

__global__ __launch_bounds__(256) void csr_scatter_kernel(
    const int* __restrict__ src, const int* __restrict__ dst,
    const int* __restrict__ rowstart, int* __restrict__ cursor,
    int* __restrict__ csr, int E)
{
    int i = blockIdx.x * 256 + threadIdx.x;
    if (i >= E) return;
    int d = dst[i];
    int pos = rowstart[d] + atomicAdd(&cursor[d], 1);
    csr[pos] = src[i];
}

// K2: GAT gather — wave per dst node, online softmax, float4 row gathers:
// 16 lanes cover one 256B row; each load instruction fetches 4 edges' rows.
__global__ __launch_bounds__(256) void gat_gather_kernel(
    const float* __restrict__ h, const float* __restrict__ a_src,
    const float* __restrict__ a_dst, const float* __restrict__ bg,
    const int* __restrict__ rowstart, const int* __restrict__ cnt,
    const int* __restrict__ csr, const float* __restrict__ wsm,
    float* __restrict__ hgat, float* __restrict__ outD, int N)
{
    const float4* __restrict__ h4 = (const float4*)h;
    int d = blockIdx.x * 4 + (threadIdx.x >> 6);
    int lane = threadIdx.x & 63;
    if (d >= N) return;
    int grp = lane >> 4;   // which of 4 edges per load
    int sub = lane & 15;   // 16B slice within row
    float ad = a_dst[d];
    int beg = rowstart[d], deg = cnt[d];
    float a0 = a_src[d] + ad;
    float m = a0 > 0.f ? a0 : NEG_SLOPE * a0;   // running max
    float l = 1.0f;                              // running denom
    // group-partial numerators (channels sub*4..+3); self-loop seeded in group 0
    float4 accA = make_float4(0.f, 0.f, 0.f, 0.f);
    float4 accB = make_float4(0.f, 0.f, 0.f, 0.f);
    if (grp == 0) accA = h4[(size_t)d * 16 + sub];
    for (int base = 0; base < deg; base += 64) {
        int eidx = base + lane;
        bool valid = eidx < deg;
        int sid = valid ? csr[beg + eidx] : 0;
        float aa = valid ? (a_src[sid] + ad) : 0.f;
        float lg = aa > 0.f ? aa : NEG_SLOPE * aa;
        if (!valid) lg = -FLT_MAX;
        float cm = lg;
        for (int off = 32; off; off >>= 1) cm = fmaxf(cm, __shfl_xor(cm, off, 64));
        float nm = fmaxf(m, cm);
        float scale = expf(m - nm);
        accA.x *= scale; accA.y *= scale; accA.z *= scale; accA.w *= scale;
        accB.x *= scale; accB.y *= scale; accB.z *= scale; accB.w *= scale;
        l *= scale; m = nm;
        float w = valid ? expf(lg - m) : 0.f;    // 0 for pad lanes
        float ws = w;
        for (int off = 32; off; off >>= 1) ws += __shfl_xor(ws, off, 64);
        l += ws;
        int nvalid = deg - base; if (nvalid > 64) nvalid = 64;
        for (int j = 0; j < nvalid; j += 16) {
            int e0 = j + grp,      e1 = j + 4 + grp;
            int e2 = j + 8 + grp,  e3 = j + 12 + grp;
            int   i0 = __shfl(sid, e0, 64); float w0 = __shfl(w, e0, 64);
            int   i1 = __shfl(sid, e1, 64); float w1 = __shfl(w, e1, 64);
            int   i2 = __shfl(sid, e2, 64); float w2 = __shfl(w, e2, 64);
            int   i3 = __shfl(sid, e3, 64); float w3 = __shfl(w, e3, 64);
            float4 v0 = h4[(size_t)i0 * 16 + sub];
            float4 v1 = h4[(size_t)i1 * 16 + sub];
            float4 v2 = h4[(size_t)i2 * 16 + sub];
            float4 v3 = h4[(size_t)i3 * 16 + sub];
            accA.x += w0 * v0.x + w1 * v1.x; accB.x += w2 * v2.x + w3 * v3.x;
            accA.y += w0 * v0.y + w1 * v1.y; accB.y += w2 * v2.y + w3 * v3.y;
            accA.z += w0 * v0.z + w1 * v1.z; accB.z += w2 * v2.z + w3 * v3.z;
            accA.w += w0 * v0.w + w1 * v1.w; accB.w += w2 * v2.w + w3 * v3.w;
        }
    }
    float4 acc;
    acc.x = accA.x + accB.x; acc.y = accA.y + accB.y;
    acc.z = accA.z + accB.z; acc.w = accA.w + accB.w;
    // combine the 4 group-partials: xor across lane bits 4,5
    #pragma unroll
    for (int off = 16; off <= 32; off <<= 1) {
        acc.x += __shfl_xor(acc.x, off, 64);
        acc.y += __shfl_xor(acc.y, off, 64);
        acc.z += __shfl_xor(acc.z, off, 64);
        acc.w += __shfl_xor(acc.w, off, 64);
    }
    float inv = 1.0f / (l + 1e-16f);
    const float4* bg4 = (const float4*)bg;
    float4 bb = bg4[sub];
    float4 out;
    out.x = acc.x * inv + bb.x; out.y = acc.y * inv + bb.y;
    out.z = acc.z * inv + bb.z; out.w = acc.w * inv + bb.w;
    size_t idx = (size_t)d * 16 + sub;
    if (grp == 0) ((float4*)hgat)[idx] = out;
    if (grp == 1) {
        float w0 = wsm[0];
        float4 o; o.x = w0 * out.x; o.y = w0 * out.y; o.z = w0 * out.z; o.w = w0 * out.w;
        ((float4*)outD)[idx] = o;
    }
}

// K3: fused SAGE layer — float4 gather-mean + (mean@Wl + hin@Wr + b)
// block = 1024 (16 waves share one LDS weight copy), wave per node
__global__ __launch_bounds__(1024) void sage_fused_kernel(
    const float* __restrict__ hin,
    const int* __restrict__ rowstart, const int* __restrict__ cnt,
    const int* __restrict__ csr,
    const float* __restrict__ Wlp, const float* __restrict__ Wrp,
    const float* __restrict__ b, const float* __restrict__ wsm, int widx,
    float* __restrict__ hout, float* __restrict__ outD, int N)
{
    __shared__ float Wl[4096];
    __shared__ float Wr[4096];
    int tid = threadIdx.x;
    ((float4*)Wl)[tid] = ((const float4*)Wlp)[tid];
    ((float4*)Wr)[tid] = ((const float4*)Wrp)[tid];
    __syncthreads();
    const float4* __restrict__ hin4 = (const float4*)hin;
    int d = blockIdx.x * 16 + (tid >> 6);
    int lane = tid & 63;
    if (d >= N) return;
    int grp = lane >> 4, sub = lane & 15;
    int beg = rowstart[d], deg = cnt[d];
    float4 s0 = make_float4(0.f,0.f,0.f,0.f), s1 = s0, s2 = s0, s3 = s0;
    for (int base = 0; base < deg; base += 64) {
        int nv = deg - base; if (nv > 64) nv = 64;
        int sid = (lane < nv) ? csr[beg + base + lane] : 0;
        for (int j = 0; j < nv; j += 16) {
            int e0 = j + grp,     e1 = j + 4 + grp;
            int e2 = j + 8 + grp, e3 = j + 12 + grp;
            int i0 = __shfl(sid, e0, 64);
            int i1 = __shfl(sid, e1, 64);
            int i2 = __shfl(sid, e2, 64);
            int i3 = __shfl(sid, e3, 64);
            if (e0 < nv) { float4 v = hin4[(size_t)i0 * 16 + sub]; s0.x += v.x; s0.y += v.y; s0.z += v.z; s0.w += v.w; }
            if (e1 < nv) { float4 v = hin4[(size_t)i1 * 16 + sub]; s1.x += v.x; s1.y += v.y; s1.z += v.z; s1.w += v.w; }
            if (e2 < nv) { float4 v = hin4[(size_t)i2 * 16 + sub]; s2.x += v.x; s2.y += v.y; s2.z += v.z; s2.w += v.w; }
            if (e3 < nv) { float4 v = hin4[(size_t)i3 * 16 + sub]; s3.x += v.x; s3.y += v.y; s3.z += v.z; s3.w += v.w; }
        }
    }
    float4 sv;
    sv.x = (s0.x + s1.x) + (s2.x + s3.x);
    sv.y = (s0.y + s1.y) + (s2.y + s3.y);
    sv.z = (s0.z + s1.z) + (s2.z + s3.z);
    sv.w = (s0.w + s1.w) + (s2.w + s3.w);
    #pragma unroll
    for (int off = 16; off <= 32; off <<= 1) {
        sv.x += __shfl_xor(sv.x, off, 64);
        sv.y += __shfl_xor(sv.y, off, 64);
        sv.z += __shfl_xor(sv.z, off, 64);
        sv.w += __shfl_xor(sv.w, off, 64);
    }
    // convert float4 slice layout -> channel=lane layout (once per node)
    int sl = lane >> 2;
    float mx = __shfl(sv.x, sl, 64);
    float my = __shfl(sv.y, sl, 64);
    float mz = __shfl(sv.z, sl, 64);
    float mw = __shfl(sv.w, sl, 64);
    int c = lane & 3;
    float sfull = (c == 0) ? mx : (c == 1) ? my : (c == 2) ? mz : mw;
    float mean = sfull / fmaxf((float)deg, 1.0f);
    float hd = hin[(size_t)d * 64 + lane];
    float acc = b[lane];
    #pragma unroll 16
    for (int k = 0; k < 64; k++) {
        acc += __shfl(mean, k, 64) * Wl[k * 64 + lane]
             + __shfl(hd,   k, 64) * Wr[k * 64 + lane];
    }
    size_t idx = (size_t)d * 64 + lane;
    if (hout) hout[idx] = acc;
    outD[idx] += wsm[widx] * acc;
}

// K4: 16 lanes per label-edge (float4 rows): out[e] = dot(outf[a], outf[b])
__global__ __launch_bounds__(256) void link_pred_kernel(
    const int* __restrict__ eli, const float* __restrict__ outf,
    float* __restrict__ out, int EL)
{
    const float4* __restrict__ o4 = (const float4*)outf;
    int e = blockIdx.x * 16 + (threadIdx.x >> 4);
    int sub = threadIdx.x & 15;
    if (e >= EL) return;
    int a = eli[e], b = eli[EL + e];
    float4 pa = o4[(size_t)a * 16 + sub];
    float4 pb = o4[(size_t)b * 16 + sub];
    float p = pa.x * pb.x + pa.y * pb.y + pa.z * pb.z + pa.w * pb.w;
    for (int off = 8; off; off >>= 1) p += __shfl_xor(p, off, 64);
    if (sub == 0) out[e] = p;
}

extern "C" void kernel_launch(void* const* d_in, const int* in_sizes, int n_in,
                              void* d_out, int out_size, void* d_ws, size_t ws_size,
                              hipStream_t stream)
{
    const float* x      = (const float*)d_in[0];
    const int*   ei     = (const int*)d_in[1];
    const int*   eli    = (const int*)d_in[2];
    const float* Wg     = (const float*)d_in[3];
    const float* att_s  = (const float*)d_in[4];
    const float* att_d  = (const float*)d_in[5];
    const float* bg     = (const float*)d_in[6];
    const float* W1l    = (const float*)d_in[7];
    const float* W1r    = (const float*)d_in[8];
    const float* b1     = (const float*)d_in[9];
    const float* W2l    = (const float*)d_in[10];
    const float* W2r    = (const float*)d_in[11];
    const float* b2     = (const float*)d_in[12];
    const float* alpha  = (const float*)d_in[13];

    const int N  = in_sizes[0] / 11;
    const int E  = in_sizes[1] / 2;
    const int EL = in_sizes[2] / 2;

    const int* src = ei;
    const int* dst = ei + E;

    // workspace layout
    float* A        = (float*)d_ws;              // N*64: h, then h1
    float* B        = A + (size_t)N * 64;        // N*64: h_gat
    float* D        = B + (size_t)N * 64;        // N*64: weighted output accumulator
    float* a_src    = D + (size_t)N * 64;        // N
    float* a_dst    = a_src + N;                 // N
    int*   cnt      = (int*)(a_dst + N);         // N (in-degree, real edges)
    int*   rowstart = cnt + N;                   // N
    int*   cursor   = rowstart + N;              // N
    int*   bsum     = cursor + N;                // 256
    int*   boff     = bsum + 256;                // 256
    int*   csr      = boff + 256;                // E (src ids grouped by dst)
    float* wsm      = (float*)(csr + E);         // 4

    hipMemsetAsync(cnt, 0, (size_t)N * sizeof(int), stream);
    hipMemsetAsync(cursor, 0, (size_t)N * sizeof(int), stream);

    softmax4_kernel<<<1, 1, 0, stream>>>(alpha, wsm);

    gat_input_kernel<<<(N + 3) / 4, 256, 0, stream>>>(x, Wg, att_s, att_d, A, a_src, a_dst, N);

    // CSR build
    csr_count_kernel<<<(E + 255) / 256, 256, 0, stream>>>(dst, cnt, E);
    int NB = (N + 1023) / 1024;
    scan_reduce_kernel<<<NB, 256, 0, stream>>>(cnt, bsum, N);
    scan_spine_kernel<<<1, 256, 0, stream>>>(bsum, boff, NB);
    scan_apply_kernel<<<NB, 256, 0, stream>>>(cnt, boff, rowstart, N);
    csr_scatter_kernel<<<(E + 255) / 256, 256, 0, stream>>>(src, dst, rowstart, cursor, csr, E);

    // GAT: read h (A) -> h_gat (B), D = w0*h_gat
    gat_gather_kernel<<<(N + 3) / 4, 256, 0, stream>>>(A, a_src, a_dst, bg,
                                                       rowstart, cnt, csr, wsm, B, D, N);

    // SAGE1: read B -> h1 (A), D += w2*h1
    sage_fused_kernel<<<(N + 15) / 16, 1024, 0, stream>>>(B, rowstart, cnt, csr,
                                                          W1l, W1r, b1, wsm, 2, A, D, N);

    // SAGE2: read A, D += w3*h2
    sage_fused_kernel<<<(N + 15) / 16, 1024, 0, stream>>>(A, rowstart, cnt, csr,
                                                          W2l, W2r, b2, wsm, 3, nullptr, D, N);

    link_pred_kernel<<<(EL + 15) / 16, 256, 0, stream>>>(eli, D, (float*)d_out, EL);
}

// Round 5
// 456.154 us; speedup vs baseline: 3.0366x; 1.5398x over previous
//
#include <hip/hip_runtime.h>
#include <math.h>
#include <float.h>

#define NEG_SLOPE 0.2f

typedef short short8 __attribute__((ext_vector_type(8)));
typedef float f32x4  __attribute__((ext_vector_type(4)));

__device__ __forceinline__ unsigned short bf16hi(float x) {
    unsigned u = __float_as_uint(x);
    return (unsigned short)((u + 0x7FFFu + ((u >> 16) & 1u)) >> 16);
}
__device__ __forceinline__ float bf16tof(unsigned short h) {
    return __uint_as_float(((unsigned)h) << 16);
}

// K0: weights = softmax(alpha), 4 elements, single thread
__global__ void softmax4_kernel(const float* __restrict__ alpha, float* __restrict__ w) {
    float m = alpha[0];
    for (int i = 1; i < 4; i++) m = fmaxf(m, alpha[i]);
    float e[4], s = 0.f;
    for (int i = 0; i < 4; i++) { e[i] = expf(alpha[i] - m); s += e[i]; }
    for (int i = 0; i < 4; i++) w[i] = e[i] / s;
}

// K1: h = x @ W_gat  (N x 11 @ 11 x 64), plus a_src = h.att_src, a_dst = h.att_dst
__global__ __launch_bounds__(256) void gat_input_kernel(
    const float* __restrict__ x, const float* __restrict__ Wg,
    const float* __restrict__ att_src, const float* __restrict__ att_dst,
    float* __restrict__ h, float* __restrict__ a_src, float* __restrict__ a_dst, int N)
{
    __shared__ float Wl[11 * 64];
    int tid = threadIdx.x;
    for (int i = tid; i < 11 * 64; i += 256) Wl[i] = Wg[i];
    __syncthreads();
    int lane = tid & 63;
    int n = blockIdx.x * 4 + (tid >> 6);
    if (n >= N) return;
    float acc = 0.f;
    #pragma unroll
    for (int k = 0; k < 11; k++) acc += x[n * 11 + k] * Wl[k * 64 + lane];
    h[(size_t)n * 64 + lane] = acc;
    float ps = acc * att_src[lane];
    float pd = acc * att_dst[lane];
    for (int off = 32; off; off >>= 1) {
        ps += __shfl_down(ps, off, 64);
        pd += __shfl_down(pd, off, 64);
    }
    if (lane == 0) { a_src[n] = ps; a_dst[n] = pd; }
}

// ---- CSR construction ----
__global__ __launch_bounds__(256) void csr_count_kernel(
    const int* __restrict__ dst, int* __restrict__ cnt, int E)
{
    int i = blockIdx.x * 256 + threadIdx.x;
    if (i < E) atomicAdd(&cnt[dst[i]], 1);
}

__global__ __launch_bounds__(256) void scan_reduce_kernel(
    const int* __restrict__ cnt, int* __restrict__ bsum, int N)
{
    __shared__ int s[256];
    int t = threadIdx.x;
    int base = blockIdx.x * 1024 + t * 4;
    int sum = 0;
    #pragma unroll
    for (int j = 0; j < 4; j++) { int idx = base + j; if (idx < N) sum += cnt[idx]; }
    s[t] = sum; __syncthreads();
    for (int off = 128; off; off >>= 1) {
        if (t < off) s[t] += s[t + off];
        __syncthreads();
    }
    if (t == 0) bsum[blockIdx.x] = s[0];
}

__global__ __launch_bounds__(256) void scan_spine_kernel(
    const int* __restrict__ bsum, int* __restrict__ boff, int NB)
{
    __shared__ int s[256];
    int t = threadIdx.x;
    int v = (t < NB) ? bsum[t] : 0;
    s[t] = v; __syncthreads();
    for (int off = 1; off < 256; off <<= 1) {
        int x = (t >= off) ? s[t - off] : 0;
        __syncthreads();
        s[t] += x;
        __syncthreads();
    }
    if (t < NB) boff[t] = s[t] - v;
}

__global__ __launch_bounds__(256) void scan_apply_kernel(
    const int* __restrict__ cnt, const int* __restrict__ boff,
    int* __restrict__ rowstart, int N)
{
    __shared__ int s[256];
    int t = threadIdx.x;
    int base = blockIdx.x * 1024;
    int v[4]; int sum = 0;
    #pragma unroll
    for (int j = 0; j < 4; j++) {
        int idx = base + t * 4 + j;
        v[j] = (idx < N) ? cnt[idx] : 0;
        sum += v[j];
    }
    s[t] = sum; __syncthreads();
    for (int off = 1; off < 256; off <<= 1) {
        int x = (t >= off) ? s[t - off] : 0;
        __syncthreads();
        s[t] += x;
        __syncthreads();
    }
    int ex = s[t] - sum + boff[blockIdx.x];
    #pragma unroll
    for (int j = 0; j < 4; j++) {
        int idx = base + t * 4 + j;
        if (idx < N) rowstart[idx] = ex;
        ex += v[j];
    }
}

__global__ __launch_bounds__(256) void csr_scatter_kernel(
    const int* __restrict__ src, const int* __restrict__ dst,
    const int* __restrict__ rowstart, int* __restrict__ cursor,
    int* __restrict__ csr, int E)
{
    int i = blockIdx.x * 256 + threadIdx.x;
    if (i >= E) return;
    int d = dst[i];
    int pos = rowstart[d] + atomicAdd(&cursor[d], 1);
    csr[pos] = src[i];
}

// K2: GAT gather — wave per dst node, online softmax, float4 row gathers
__global__ __launch_bounds__(256) void gat_gather_kernel(
    const float* __restrict__ h, const float* __restrict__ a_src,
    const float* __restrict__ a_dst, const float* __restrict__ bg,
    const int* __restrict__ rowstart, const int* __restrict__ cnt,
    const int* __restrict__ csr, const float* __restrict__ wsm,
    float* __restrict__ hgat, float* __restrict__ outD, int N)
{
    const float4* __restrict__ h4 = (const float4*)h;
    int d = blockIdx.x * 4 + (threadIdx.x >> 6);
    int lane = threadIdx.x & 63;
    if (d >= N) return;
    int grp = lane >> 4;
    int sub = lane & 15;
    float ad = a_dst[d];
    int beg = rowstart[d], deg = cnt[d];
    float a0 = a_src[d] + ad;
    float m = a0 > 0.f ? a0 : NEG_SLOPE * a0;
    float l = 1.0f;
    float4 accA = make_float4(0.f, 0.f, 0.f, 0.f);
    float4 accB = make_float4(0.f, 0.f, 0.f, 0.f);
    if (grp == 0) accA = h4[(size_t)d * 16 + sub];
    for (int base = 0; base < deg; base += 64) {
        int eidx = base + lane;
        bool valid = eidx < deg;
        int sid = valid ? csr[beg + eidx] : 0;
        float aa = valid ? (a_src[sid] + ad) : 0.f;
        float lg = aa > 0.f ? aa : NEG_SLOPE * aa;
        if (!valid) lg = -FLT_MAX;
        float cm = lg;
        for (int off = 32; off; off >>= 1) cm = fmaxf(cm, __shfl_xor(cm, off, 64));
        float nm = fmaxf(m, cm);
        float scale = expf(m - nm);
        accA.x *= scale; accA.y *= scale; accA.z *= scale; accA.w *= scale;
        accB.x *= scale; accB.y *= scale; accB.z *= scale; accB.w *= scale;
        l *= scale; m = nm;
        float w = valid ? expf(lg - m) : 0.f;
        float ws = w;
        for (int off = 32; off; off >>= 1) ws += __shfl_xor(ws, off, 64);
        l += ws;
        int nvalid = deg - base; if (nvalid > 64) nvalid = 64;
        for (int j = 0; j < nvalid; j += 16) {
            int e0 = j + grp,      e1 = j + 4 + grp;
            int e2 = j + 8 + grp,  e3 = j + 12 + grp;
            int   i0 = __shfl(sid, e0, 64); float w0 = __shfl(w, e0, 64);
            int   i1 = __shfl(sid, e1, 64); float w1 = __shfl(w, e1, 64);
            int   i2 = __shfl(sid, e2, 64); float w2 = __shfl(w, e2, 64);
            int   i3 = __shfl(sid, e3, 64); float w3 = __shfl(w, e3, 64);
            float4 v0 = h4[(size_t)i0 * 16 + sub];
            float4 v1 = h4[(size_t)i1 * 16 + sub];
            float4 v2 = h4[(size_t)i2 * 16 + sub];
            float4 v3 = h4[(size_t)i3 * 16 + sub];
            accA.x += w0 * v0.x + w1 * v1.x; accB.x += w2 * v2.x + w3 * v3.x;
            accA.y += w0 * v0.y + w1 * v1.y; accB.y += w2 * v2.y + w3 * v3.y;
            accA.z += w0 * v0.z + w1 * v1.z; accB.z += w2 * v2.z + w3 * v3.z;
            accA.w += w0 * v0.w + w1 * v1.w; accB.w += w2 * v2.w + w3 * v3.w;
        }
    }
    float4 acc;
    acc.x = accA.x + accB.x; acc.y = accA.y + accB.y;
    acc.z = accA.z + accB.z; acc.w = accA.w + accB.w;
    #pragma unroll
    for (int off = 16; off <= 32; off <<= 1) {
        acc.x += __shfl_xor(acc.x, off, 64);
        acc.y += __shfl_xor(acc.y, off, 64);
        acc.z += __shfl_xor(acc.z, off, 64);
        acc.w += __shfl_xor(acc.w, off, 64);
    }
    float inv = 1.0f / (l + 1e-16f);
    const float4* bg4 = (const float4*)bg;
    float4 bb = bg4[sub];
    float4 out;
    out.x = acc.x * inv + bb.x; out.y = acc.y * inv + bb.y;
    out.z = acc.z * inv + bb.z; out.w = acc.w * inv + bb.w;
    size_t idx = (size_t)d * 16 + sub;
    if (grp == 0) ((float4*)hgat)[idx] = out;
    if (grp == 1) {
        float w0 = wsm[0];
        float4 o; o.x = w0 * out.x; o.y = w0 * out.y; o.z = w0 * out.z; o.w = w0 * out.w;
        ((float4*)outD)[idx] = o;
    }
}

// K5: convert [Wl|Wr] (64x128 fp32, k-major) into MFMA b-frag layout, bf16 hi/lo.
// frag buffer: [kc(2)][t(8)][lane(64)][j(8)]; b-frag element = W[kc*32+quad*8+j][t*16+col16]
__global__ __launch_bounds__(256) void wprep_kernel(
    const float* __restrict__ Wl, const float* __restrict__ Wr,
    unsigned short* __restrict__ Whi, unsigned short* __restrict__ Wlo)
{
    int idx = blockIdx.x * 256 + threadIdx.x;   // 0..1023
    if (idx >= 1024) return;
    int kc = idx >> 9, rem = idx & 511;
    int t = rem >> 6, lane = rem & 63;
    int quad = lane >> 4, col16 = lane & 15;
    int c = t * 16 + col16;
    #pragma unroll
    for (int j = 0; j < 8; j++) {
        int k = kc * 32 + quad * 8 + j;
        float w = (c < 64) ? Wl[k * 64 + c] : Wr[k * 64 + (c - 64)];
        unsigned short hi = bf16hi(w);
        unsigned short lo = bf16hi(w - bf16tof(hi));
        Whi[(size_t)idx * 8 + j] = hi;
        Wlo[(size_t)idx * 8 + j] = lo;
    }
}

// K6: dense GEMM [P|Q] = hin @ [Wl|Wr] (+b on Q half) via mfma 16x16x32 bf16x3.
// Block 256 = 4 waves; wave handles 16 rows x 128 cols. Q written IN-PLACE over hin
// (each wave reads/writes only its own 16 rows).
__global__ __launch_bounds__(256) void sage_gemm_kernel(
    const float* __restrict__ hin,
    const unsigned short* __restrict__ Whi, const unsigned short* __restrict__ Wlo,
    const float* __restrict__ bvec,
    float* __restrict__ P, float* __restrict__ Q, int N)
{
    int wave = threadIdx.x >> 6, lane = threadIdx.x & 63;
    int base = blockIdx.x * 64 + wave * 16;
    if (base >= N) return;
    int quad = lane >> 4, col16 = lane & 15;
    int m = base + col16;
    int mc = m < N ? m : N - 1;
    f32x4 acc[8];
    #pragma unroll
    for (int t = 0; t < 8; t++) acc[t] = (f32x4){0.f, 0.f, 0.f, 0.f};
    #pragma unroll
    for (int kc = 0; kc < 2; kc++) {
        const float* ap = hin + (size_t)mc * 64 + kc * 32 + quad * 8;
        float4 va = *(const float4*)ap;
        float4 vb = *(const float4*)(ap + 4);
        float av[8] = {va.x, va.y, va.z, va.w, vb.x, vb.y, vb.z, vb.w};
        short8 ahi, alo;
        #pragma unroll
        for (int j = 0; j < 8; j++) {
            unsigned short hh = bf16hi(av[j]);
            ahi[j] = (short)hh;
            alo[j] = (short)bf16hi(av[j] - bf16tof(hh));
        }
        #pragma unroll
        for (int t = 0; t < 8; t++) {
            size_t off = ((size_t)(kc * 8 + t) * 64 + lane) * 8;
            short8 bhi = *(const short8*)(Whi + off);
            short8 blo = *(const short8*)(Wlo + off);
            acc[t] = __builtin_amdgcn_mfma_f32_16x16x32_bf16(ahi, bhi, acc[t], 0, 0, 0);
            acc[t] = __builtin_amdgcn_mfma_f32_16x16x32_bf16(alo, bhi, acc[t], 0, 0, 0);
            acc[t] = __builtin_amdgcn_mfma_f32_16x16x32_bf16(ahi, blo, acc[t], 0, 0, 0);
        }
    }
    // epilogue: D row = quad*4 + r, col = t*16 + col16
    #pragma unroll
    for (int t = 0; t < 8; t++) {
        #pragma unroll
        for (int r = 0; r < 4; r++) {
            int node = base + quad * 4 + r;
            if (node < N) {
                float v = acc[t][r];
                if (t < 4) {
                    P[(size_t)node * 64 + t * 16 + col16] = v;
                } else {
                    int c = (t - 4) * 16 + col16;
                    Q[(size_t)node * 64 + c] = v + bvec[c];
                }
            }
        }
    }
}

// K7: SAGE post — h' = mean_nbr(P) + Q[d]; outD += w*h'; optional hout store.
// No LDS, no matmul: pure float4 gather.
__global__ __launch_bounds__(256) void sage_post_kernel(
    const float* __restrict__ P, const float* __restrict__ Q,
    const int* __restrict__ rowstart, const int* __restrict__ cnt,
    const int* __restrict__ csr, const float* __restrict__ wsm, int widx,
    float* __restrict__ hout, float* __restrict__ outD, int N)
{
    const float4* __restrict__ P4 = (const float4*)P;
    int d = blockIdx.x * 4 + (threadIdx.x >> 6);
    int lane = threadIdx.x & 63;
    if (d >= N) return;
    int grp = lane >> 4, sub = lane & 15;
    int beg = rowstart[d], deg = cnt[d];
    float4 s0 = make_float4(0.f,0.f,0.f,0.f), s1 = s0, s2 = s0, s3 = s0;
    for (int base = 0; base < deg; base += 64) {
        int nv = deg - base; if (nv > 64) nv = 64;
        int sid = (lane < nv) ? csr[beg + base + lane] : 0;
        for (int j = 0; j < nv; j += 16) {
            int e0 = j + grp,     e1 = j + 4 + grp;
            int e2 = j + 8 + grp, e3 = j + 12 + grp;
            int i0 = __shfl(sid, e0, 64);
            int i1 = __shfl(sid, e1, 64);
            int i2 = __shfl(sid, e2, 64);
            int i3 = __shfl(sid, e3, 64);
            if (e0 < nv) { float4 v = P4[(size_t)i0 * 16 + sub]; s0.x += v.x; s0.y += v.y; s0.z += v.z; s0.w += v.w; }
            if (e1 < nv) { float4 v = P4[(size_t)i1 * 16 + sub]; s1.x += v.x; s1.y += v.y; s1.z += v.z; s1.w += v.w; }
            if (e2 < nv) { float4 v = P4[(size_t)i2 * 16 + sub]; s2.x += v.x; s2.y += v.y; s2.z += v.z; s2.w += v.w; }
            if (e3 < nv) { float4 v = P4[(size_t)i3 * 16 + sub]; s3.x += v.x; s3.y += v.y; s3.z += v.z; s3.w += v.w; }
        }
    }
    float4 sv;
    sv.x = (s0.x + s1.x) + (s2.x + s3.x);
    sv.y = (s0.y + s1.y) + (s2.y + s3.y);
    sv.z = (s0.z + s1.z) + (s2.z + s3.z);
    sv.w = (s0.w + s1.w) + (s2.w + s3.w);
    #pragma unroll
    for (int off = 16; off <= 32; off <<= 1) {
        sv.x += __shfl_xor(sv.x, off, 64);
        sv.y += __shfl_xor(sv.y, off, 64);
        sv.z += __shfl_xor(sv.z, off, 64);
        sv.w += __shfl_xor(sv.w, off, 64);
    }
    float invd = 1.0f / fmaxf((float)deg, 1.0f);
    size_t idx = (size_t)d * 16 + sub;
    float4 q4 = ((const float4*)Q)[idx];
    float4 o;
    o.x = sv.x * invd + q4.x; o.y = sv.y * invd + q4.y;
    o.z = sv.z * invd + q4.z; o.w = sv.w * invd + q4.w;
    if (hout && grp == 0) ((float4*)hout)[idx] = o;
    if (grp == 1) {
        float w = wsm[widx];
        float4 dd = ((float4*)outD)[idx];
        dd.x += w * o.x; dd.y += w * o.y; dd.z += w * o.z; dd.w += w * o.w;
        ((float4*)outD)[idx] = dd;
    }
}

// K8: 16 lanes per label-edge (float4 rows): out[e] = dot(outf[a], outf[b])
__global__ __launch_bounds__(256) void link_pred_kernel(
    const int* __restrict__ eli, const float* __restrict__ outf,
    float* __restrict__ out, int EL)
{
    const float4* __restrict__ o4 = (const float4*)outf;
    int e = blockIdx.x * 16 + (threadIdx.x >> 4);
    int sub = threadIdx.x & 15;
    if (e >= EL) return;
    int a = eli[e], b = eli[EL + e];
    float4 pa = o4[(size_t)a * 16 + sub];
    float4 pb = o4[(size_t)b * 16 + sub];
    float p = pa.x * pb.x + pa.y * pb.y + pa.z * pb.z + pa.w * pb.w;
    for (int off = 8; off; off >>= 1) p += __shfl_xor(p, off, 64);
    if (sub == 0) out[e] = p;
}

extern "C" void kernel_launch(void* const* d_in, const int* in_sizes, int n_in,
                              void* d_out, int out_size, void* d_ws, size_t ws_size,
                              hipStream_t stream)
{
    const float* x      = (const float*)d_in[0];
    const int*   ei     = (const int*)d_in[1];
    const int*   eli    = (const int*)d_in[2];
    const float* Wg     = (const float*)d_in[3];
    const float* att_s  = (const float*)d_in[4];
    const float* att_d  = (const float*)d_in[5];
    const float* bg     = (const float*)d_in[6];
    const float* W1l    = (const float*)d_in[7];
    const float* W1r    = (const float*)d_in[8];
    const float* b1     = (const float*)d_in[9];
    const float* W2l    = (const float*)d_in[10];
    const float* W2r    = (const float*)d_in[11];
    const float* b2     = (const float*)d_in[12];
    const float* alpha  = (const float*)d_in[13];

    const int N  = in_sizes[0] / 11;
    const int E  = in_sizes[1] / 2;
    const int EL = in_sizes[2] / 2;

    const int* src = ei;
    const int* dst = ei + E;

    // workspace layout
    float* A        = (float*)d_ws;              // N*64: h -> P1 -> P2
    float* B        = A + (size_t)N * 64;        // N*64: h_gat -> Q1/h1 (in-place) -> Q2
    float* D        = B + (size_t)N * 64;        // N*64: weighted output accumulator
    float* a_src    = D + (size_t)N * 64;        // N
    float* a_dst    = a_src + N;                 // N
    int*   cnt      = (int*)(a_dst + N);         // N
    int*   rowstart = cnt + N;                   // N
    int*   cursor   = rowstart + N;              // N
    int*   bsum     = cursor + N;                // 256
    int*   boff     = bsum + 256;                // 256
    int*   csr      = boff + 256;                // E
    unsigned short* wf = (unsigned short*)(csr + E);  // 4 x 8192 ushorts (16B-aligned)
    unsigned short* W1hi = wf;
    unsigned short* W1lo = wf + 8192;
    unsigned short* W2hi = wf + 16384;
    unsigned short* W2lo = wf + 24576;
    float* wsm      = (float*)(wf + 32768);      // 4

    hipMemsetAsync(cnt, 0, (size_t)N * sizeof(int), stream);
    hipMemsetAsync(cursor, 0, (size_t)N * sizeof(int), stream);

    softmax4_kernel<<<1, 1, 0, stream>>>(alpha, wsm);
    wprep_kernel<<<4, 256, 0, stream>>>(W1l, W1r, W1hi, W1lo);
    wprep_kernel<<<4, 256, 0, stream>>>(W2l, W2r, W2hi, W2lo);

    gat_input_kernel<<<(N + 3) / 4, 256, 0, stream>>>(x, Wg, att_s, att_d, A, a_src, a_dst, N);

    // CSR build
    csr_count_kernel<<<(E + 255) / 256, 256, 0, stream>>>(dst, cnt, E);
    int NB = (N + 1023) / 1024;
    scan_reduce_kernel<<<NB, 256, 0, stream>>>(cnt, bsum, N);
    scan_spine_kernel<<<1, 256, 0, stream>>>(bsum, boff, NB);
    scan_apply_kernel<<<NB, 256, 0, stream>>>(cnt, boff, rowstart, N);
    csr_scatter_kernel<<<(E + 255) / 256, 256, 0, stream>>>(src, dst, rowstart, cursor, csr, E);

    // GAT: read h (A) -> h_gat (B), D = w0*h_gat
    gat_gather_kernel<<<(N + 3) / 4, 256, 0, stream>>>(A, a_src, a_dst, bg,
                                                       rowstart, cnt, csr, wsm, B, D, N);

    // SAGE1: GEMM reads B(hgat): P1 -> A, Q1 -> B (in-place). post: h1 -> B, D += w2*h1
    sage_gemm_kernel<<<(N + 63) / 64, 256, 0, stream>>>(B, W1hi, W1lo, b1, A, B, N);
    sage_post_kernel<<<(N + 3) / 4, 256, 0, stream>>>(A, B, rowstart, cnt, csr, wsm, 2, B, D, N);

    // SAGE2: GEMM reads B(h1): P2 -> A, Q2 -> B (in-place). post: D += w3*h2
    sage_gemm_kernel<<<(N + 63) / 64, 256, 0, stream>>>(B, W2hi, W2lo, b2, A, B, N);
    sage_post_kernel<<<(N + 3) / 4, 256, 0, stream>>>(A, B, rowstart, cnt, csr, wsm, 3, nullptr, D, N);

    link_pred_kernel<<<(EL + 15) / 16, 256, 0, stream>>>(eli, D, (float*)d_out, EL);
}